// Round 1
// baseline (1262.991 us; speedup 1.0000x reference)
//
#include <hip/hip_runtime.h>
#include <stdint.h>

typedef unsigned short u16;
typedef __attribute__((ext_vector_type(8))) short short8;
typedef __attribute__((ext_vector_type(4))) float f32x4;

#define NSTEP 26
#define NB 512
#define NT 128
#define NH 256
#define NCLS 100

__device__ __forceinline__ float bf2f(u16 s) { return __uint_as_float(((unsigned)s) << 16); }
__device__ __forceinline__ u16 f2bf(float f) {
    unsigned u = __float_as_uint(f);
    return (u16)((u + 0x7FFFu + ((u >> 16) & 1u)) >> 16);
}
__device__ __forceinline__ float fast_tanh(float x) {
    float e = __expf(2.f * x);
    return 1.f - 2.f / (e + 1.f);
}
__device__ __forceinline__ float fast_sig(float x) { return 1.f / (1.f + __expf(-x)); }

// ---------------- prep: weight conversions ----------------
__global__ void prep_weights(const float* __restrict__ W_h2h, const float* __restrict__ W_ih,
                             const float* __restrict__ W_hh, const float* __restrict__ b_ih,
                             const float* __restrict__ b_hh, const float* __restrict__ W_gen,
                             u16* __restrict__ W_h2h_bf, u16* __restrict__ Wcat,
                             float* __restrict__ bsum, u16* __restrict__ WgenP) {
    int idx = blockIdx.x * 256 + threadIdx.x;
    if (idx < 256 * 256) W_h2h_bf[idx] = f2bf(W_h2h[idx]);
    // Wcat [1024][512] = [W_ih[:, :256] | W_hh]
    for (int i = idx; i < 1024 * 512; i += gridDim.x * 256) {
        int r = i >> 9, c = i & 511;
        float v = (c < 256) ? W_ih[r * 356 + c] : W_hh[r * 256 + (c - 256)];
        Wcat[i] = f2bf(v);
    }
    if (idx < 1024) bsum[idx] = b_ih[idx] + b_hh[idx];
    if (idx < 128 * 256) {
        int r = idx >> 8, c = idx & 255;
        WgenP[idx] = (r < NCLS) ? f2bf(W_gen[r * 256 + c]) : (u16)0;
    }
}

// ---------------- batch_H -> bf16 copy (same layout [b][t][i]) ----------------
__global__ void conv_bH(const float* __restrict__ bH, u16* __restrict__ bHb) {
    int idx = blockIdx.x * 256 + threadIdx.x;  // 4,194,304 threads, 4 elems each
    const float4* p = reinterpret_cast<const float4*>(bH);
    float4 v = p[idx];
    ushort4 o;
    o.x = f2bf(v.x); o.y = f2bf(v.y); o.z = f2bf(v.z); o.w = f2bf(v.w);
    reinterpret_cast<ushort4*>(bHb)[idx] = o;
}

// ---------------- proj_HT[b][h][t] = (batch_H @ W_i2h^T) transposed, bf16 ----------------
__launch_bounds__(256)
__global__ void gemm_projH(const float* __restrict__ bH, const float* __restrict__ W_i2h,
                           u16* __restrict__ projHT) {
    __shared__ u16 As[64 * 32];
    __shared__ u16 Bs[64 * 32];
    int mb = blockIdx.x;  // 1024 tiles of 64 rows (m = b*128+t)
    int nb = blockIdx.y;  // 4 tiles of 64 cols (h)
    int tid = threadIdx.x;
    int wave = tid >> 6, lane = tid & 63;
    int wm = wave >> 1, wn = wave & 1;
    int lr = lane & 15, lq = lane >> 4;
    f32x4 acc[2][2] = {};
    for (int kc = 0; kc < 256; kc += 32) {
        __syncthreads();
        {
            int r = tid >> 2, c = (tid & 3) * 8;
            const float* src = bH + (size_t)(mb * 64 + r) * 256 + kc + c;
            float4 v0 = *(const float4*)(src);
            float4 v1 = *(const float4*)(src + 4);
            u16* dst = As + r * 32 + c;
            dst[0] = f2bf(v0.x); dst[1] = f2bf(v0.y); dst[2] = f2bf(v0.z); dst[3] = f2bf(v0.w);
            dst[4] = f2bf(v1.x); dst[5] = f2bf(v1.y); dst[6] = f2bf(v1.z); dst[7] = f2bf(v1.w);
        }
        {
            int r = tid >> 2, c = (tid & 3) * 8;
            const float* src = W_i2h + (size_t)(nb * 64 + r) * 256 + kc + c;
            float4 v0 = *(const float4*)(src);
            float4 v1 = *(const float4*)(src + 4);
            u16* dst = Bs + r * 32 + c;
            dst[0] = f2bf(v0.x); dst[1] = f2bf(v0.y); dst[2] = f2bf(v0.z); dst[3] = f2bf(v0.w);
            dst[4] = f2bf(v1.x); dst[5] = f2bf(v1.y); dst[6] = f2bf(v1.z); dst[7] = f2bf(v1.w);
        }
        __syncthreads();
        for (int mi = 0; mi < 2; mi++) {
            short8 a = *reinterpret_cast<const short8*>(As + (wm * 32 + mi * 16 + lr) * 32 + lq * 8);
            for (int ni = 0; ni < 2; ni++) {
                short8 b = *reinterpret_cast<const short8*>(Bs + (wn * 32 + ni * 16 + lr) * 32 + lq * 8);
                acc[mi][ni] = __builtin_amdgcn_mfma_f32_16x16x32_bf16(a, b, acc[mi][ni], 0, 0, 0);
            }
        }
    }
    for (int mi = 0; mi < 2; mi++)
        for (int ni = 0; ni < 2; ni++) {
            int n = nb * 64 + wn * 32 + ni * 16 + lr;       // h
            int m = mb * 64 + wm * 32 + mi * 16 + lq * 4;   // b*128+t
            int b = m >> 7, t = m & 127;
            u16* dst = projHT + (size_t)b * (256 * 128) + n * 128 + t;
            f32x4 v = acc[mi][ni];
            dst[0] = f2bf(v[0]); dst[1] = f2bf(v[1]); dst[2] = f2bf(v[2]); dst[3] = f2bf(v[3]);
        }
}

// ---------------- per-step fused attention: proj_h + e + softmax + context ----------------
__launch_bounds__(256)
__global__ void attn_step(const float* __restrict__ h_all, const u16* __restrict__ W_h2h_bf,
                          const float* __restrict__ b_h2h, const float* __restrict__ W_score,
                          const u16* __restrict__ projHT, const u16* __restrict__ bHb,
                          u16* __restrict__ Xcat, int step) {
    __shared__ float h_s[256];
    __shared__ float ph[256];
    __shared__ float epart[256];
    __shared__ float e_s[128];
    __shared__ float red[2];
    int b = blockIdx.x, tid = threadIdx.x;

    float hv = (step > 0) ? h_all[(size_t)(step - 1) * NB * NH + b * NH + tid] : 0.f;
    h_s[tid] = hv;
    Xcat[b * 512 + 256 + tid] = f2bf(hv);  // h half of LSTM input
    __syncthreads();

    // proj_h[n] = b_h2h[n] + h . W_h2h[n,:]
    {
        float acc = b_h2h[tid];
        const u16* wrow = W_h2h_bf + tid * 256;
        for (int k = 0; k < 256; k += 8) {
            ushort4 w0 = *(const ushort4*)(wrow + k);
            ushort4 w1 = *(const ushort4*)(wrow + k + 4);
            acc += h_s[k + 0] * bf2f(w0.x) + h_s[k + 1] * bf2f(w0.y) +
                   h_s[k + 2] * bf2f(w0.z) + h_s[k + 3] * bf2f(w0.w) +
                   h_s[k + 4] * bf2f(w1.x) + h_s[k + 5] * bf2f(w1.y) +
                   h_s[k + 6] * bf2f(w1.z) + h_s[k + 7] * bf2f(w1.w);
        }
        ph[tid] = acc;
    }
    __syncthreads();

    // e[t] = sum_h tanh(projHT[b][h][t] + ph[h]) * W_score[h], split over 2 halves of h
    {
        int t = tid & 127, half = tid >> 7;
        const u16* base = projHT + (size_t)b * 32768 + (half * 128) * 128 + t;
        float acc = 0.f;
        for (int kk = 0; kk < 128; kk++) {
            float x = bf2f(base[kk * 128]) + ph[half * 128 + kk];
            acc += fast_tanh(x) * W_score[half * 128 + kk];
        }
        epart[tid] = acc;
    }
    __syncthreads();
    if (tid < 128) e_s[tid] = epart[tid] + epart[tid + 128];
    __syncthreads();

    // softmax over t=0..127
    if (tid < 64) {
        float v = fmaxf(e_s[tid], e_s[tid + 64]);
        for (int o = 32; o >= 1; o >>= 1) v = fmaxf(v, __shfl_down(v, o));
        if (tid == 0) red[0] = v;
    }
    __syncthreads();
    float mx = red[0];
    if (tid < 128) e_s[tid] = __expf(e_s[tid] - mx);
    __syncthreads();
    if (tid < 64) {
        float v = e_s[tid] + e_s[tid + 64];
        for (int o = 32; o >= 1; o >>= 1) v += __shfl_down(v, o);
        if (tid == 0) red[1] = 1.f / v;
    }
    __syncthreads();
    float rinv = red[1];

    // context[i] = (sum_t alpha[t] * batch_H[b][t][i]) / sum
    {
        const u16* base = bHb + (size_t)b * 32768 + tid;
        float acc = 0.f;
        for (int t = 0; t < 128; t++) acc += e_s[t] * bf2f(base[t * 256]);
        Xcat[b * 512 + tid] = f2bf(acc * rinv);
    }
}

// ---------------- per-step LSTM: gates GEMM (MFMA) + onehot col + pointwise ----------------
__launch_bounds__(256)
__global__ void lstm_step(const u16* __restrict__ Xcat, const u16* __restrict__ Wcat,
                          const float* __restrict__ bsum, const float* __restrict__ W_ih,
                          const int* __restrict__ text, float* __restrict__ c_st,
                          float* __restrict__ h_all, u16* __restrict__ hbf_all, int step) {
    __shared__ u16 Xs[32 * 32];
    __shared__ u16 Ws[128 * 32];
    __shared__ float gsum[32 * 128];
    int b0 = blockIdx.x * 32;  // 16 blocks in x
    int u0 = blockIdx.y * 32;  // 8 blocks in y: units u0..u0+31 (gate rows u, u+256, u+512, u+768)
    int tid = threadIdx.x;
    int wave = tid >> 6, lane = tid & 63, lr = lane & 15, lq = lane >> 4;
    int wm = wave >> 1, wn = wave & 1;
    f32x4 acc[4] = {};

    for (int kc = 0; kc < 512; kc += 32) {
        __syncthreads();
        {
            int r = tid >> 3, c4 = (tid & 7) * 4;
            *(ushort4*)(Xs + r * 32 + c4) = *(const ushort4*)(Xcat + (size_t)(b0 + r) * 512 + kc + c4);
        }
        {
            int ln = tid >> 1, h16 = (tid & 1) * 16;
            int grow = (ln >> 5) * 256 + u0 + (ln & 31);  // quad*256 + unit
            const u16* src = Wcat + (size_t)grow * 512 + kc + h16;
            u16* d = Ws + ln * 32 + h16;
            *(ushort4*)(d) = *(const ushort4*)(src);
            *(ushort4*)(d + 4) = *(const ushort4*)(src + 4);
            *(ushort4*)(d + 8) = *(const ushort4*)(src + 8);
            *(ushort4*)(d + 12) = *(const ushort4*)(src + 12);
        }
        __syncthreads();
        short8 a = *reinterpret_cast<const short8*>(Xs + (wm * 16 + lr) * 32 + lq * 8);
        for (int ni = 0; ni < 4; ni++) {
            short8 bb = *reinterpret_cast<const short8*>(Ws + (wn * 64 + ni * 16 + lr) * 32 + lq * 8);
            acc[ni] = __builtin_amdgcn_mfma_f32_16x16x32_bf16(a, bb, acc[ni], 0, 0, 0);
        }
    }
    for (int ni = 0; ni < 4; ni++) {
        int n = wn * 64 + ni * 16 + lr;
        int m = wm * 16 + lq * 4;
        gsum[(m + 0) * 128 + n] = acc[ni][0];
        gsum[(m + 1) * 128 + n] = acc[ni][1];
        gsum[(m + 2) * 128 + n] = acc[ni][2];
        gsum[(m + 3) * 128 + n] = acc[ni][3];
    }
    __syncthreads();

    int m = tid >> 3;
    int bg = b0 + m;
    int tgt = text[bg * NSTEP + step];
    for (int j = 0; j < 4; j++) {
        int uu = (tid & 7) * 4 + j;
        int u = u0 + uu;
        int ri = u, rf = 256 + u, rg = 512 + u, ro = 768 + u;
        float gi = gsum[m * 128 + 0 * 32 + uu] + bsum[ri] + W_ih[(size_t)ri * 356 + 256 + tgt];
        float gf = gsum[m * 128 + 1 * 32 + uu] + bsum[rf] + W_ih[(size_t)rf * 356 + 256 + tgt];
        float gg = gsum[m * 128 + 2 * 32 + uu] + bsum[rg] + W_ih[(size_t)rg * 356 + 256 + tgt];
        float go = gsum[m * 128 + 3 * 32 + uu] + bsum[ro] + W_ih[(size_t)ro * 356 + 256 + tgt];
        float cold = (step > 0) ? c_st[bg * 256 + u] : 0.f;
        float cn = fast_sig(gf) * cold + fast_sig(gi) * fast_tanh(gg);
        float hn = fast_sig(go) * fast_tanh(cn);
        c_st[bg * 256 + u] = cn;
        h_all[(size_t)step * NB * NH + bg * 256 + u] = hn;
        hbf_all[(size_t)step * NB * NH + bg * 256 + u] = f2bf(hn);
    }
}

// ---------------- final: logits = h_all @ W_gen^T + b_gen; blank = -10000 ----------------
__launch_bounds__(256)
__global__ void gen_logits(const u16* __restrict__ hbf_all, const u16* __restrict__ WgenP,
                           const float* __restrict__ b_gen, float* __restrict__ out) {
    __shared__ u16 As[32 * 32];
    __shared__ u16 Bs[128 * 32];
    int mb = blockIdx.x;  // 416 tiles of 32 rows (m = s*512 + b)
    int tid = threadIdx.x;
    int wave = tid >> 6, lane = tid & 63, lr = lane & 15, lq = lane >> 4;
    int wm = wave >> 1, wn = wave & 1;
    f32x4 acc[4] = {};
    for (int kc = 0; kc < 256; kc += 32) {
        __syncthreads();
        {
            int r = tid >> 3, c4 = (tid & 7) * 4;
            *(ushort4*)(As + r * 32 + c4) =
                *(const ushort4*)(hbf_all + (size_t)(mb * 32 + r) * 256 + kc + c4);
        }
        {
            int r = tid >> 1, h16 = (tid & 1) * 16;
            const u16* src = WgenP + (size_t)r * 256 + kc + h16;
            u16* d = Bs + r * 32 + h16;
            *(ushort4*)(d) = *(const ushort4*)(src);
            *(ushort4*)(d + 4) = *(const ushort4*)(src + 4);
            *(ushort4*)(d + 8) = *(const ushort4*)(src + 8);
            *(ushort4*)(d + 12) = *(const ushort4*)(src + 12);
        }
        __syncthreads();
        short8 a = *reinterpret_cast<const short8*>(As + (wm * 16 + lr) * 32 + lq * 8);
        for (int ni = 0; ni < 4; ni++) {
            short8 bb = *reinterpret_cast<const short8*>(Bs + (wn * 64 + ni * 16 + lr) * 32 + lq * 8);
            acc[ni] = __builtin_amdgcn_mfma_f32_16x16x32_bf16(a, bb, acc[ni], 0, 0, 0);
        }
    }
    for (int ni = 0; ni < 4; ni++) {
        int cidx = wn * 64 + ni * 16 + lr;
        if (cidx >= NCLS) continue;
        float bg = b_gen[cidx];
        int mbase = mb * 32 + wm * 16 + lq * 4;
        for (int r = 0; r < 4; r++) {
            int mm = mbase + r;
            int s = mm >> 9;       // m = s*512 + b
            int bb_ = mm & 511;
            float v = (cidx == 3) ? -10000.f : (acc[ni][r] + bg);
            out[(size_t)bb_ * (NSTEP * NCLS) + s * NCLS + cidx] = v;
        }
    }
}

extern "C" void kernel_launch(void* const* d_in, const int* in_sizes, int n_in,
                              void* d_out, int out_size, void* d_ws, size_t ws_size,
                              hipStream_t stream) {
    const float* batch_H = (const float*)d_in[0];
    const int* text = (const int*)d_in[1];
    const float* W_i2h = (const float*)d_in[3];
    const float* W_h2h = (const float*)d_in[4];
    const float* b_h2h = (const float*)d_in[5];
    const float* W_score = (const float*)d_in[6];
    const float* W_ih = (const float*)d_in[7];
    const float* W_hh = (const float*)d_in[8];
    const float* b_ih = (const float*)d_in[9];
    const float* b_hh = (const float*)d_in[10];
    const float* W_gen = (const float*)d_in[11];
    const float* b_gen = (const float*)d_in[12];
    float* out = (float*)d_out;

    char* ws = (char*)d_ws;
    size_t off = 0;
    auto alloc = [&](size_t bytes) {
        void* p = ws + off;
        off += (bytes + 255) & ~(size_t)255;
        return p;
    };
    u16* bHb = (u16*)alloc((size_t)16777216 * 2);     // batch_H bf16 [b][t][i]
    u16* projHT = (u16*)alloc((size_t)16777216 * 2);  // proj_H bf16 transposed [b][h][t]
    u16* W_h2h_bf = (u16*)alloc(65536 * 2);
    u16* Wcat = (u16*)alloc(524288 * 2);              // [1024][512]
    float* bsum = (float*)alloc(1024 * 4);
    u16* WgenP = (u16*)alloc(32768 * 2);              // [128][256]
    u16* Xcat = (u16*)alloc(262144 * 2);              // [512][512] = [context|h]
    float* h_all = (float*)alloc((size_t)NSTEP * NB * NH * 4);
    u16* hbf_all = (u16*)alloc((size_t)NSTEP * NB * NH * 2);
    float* c_st = (float*)alloc((size_t)NB * NH * 4);

    prep_weights<<<256, 256, 0, stream>>>(W_h2h, W_ih, W_hh, b_ih, b_hh, W_gen,
                                          W_h2h_bf, Wcat, bsum, WgenP);
    conv_bH<<<16384, 256, 0, stream>>>(batch_H, bHb);
    gemm_projH<<<dim3(1024, 4), 256, 0, stream>>>(batch_H, W_i2h, projHT);
    for (int s = 0; s < NSTEP; s++) {
        attn_step<<<512, 256, 0, stream>>>(h_all, W_h2h_bf, b_h2h, W_score, projHT, bHb, Xcat, s);
        lstm_step<<<dim3(16, 8), 256, 0, stream>>>(Xcat, Wcat, bsum, W_ih, text, c_st,
                                                   h_all, hbf_all, s);
    }
    gen_logits<<<416, 256, 0, stream>>>(hbf_all, WgenP, b_gen, out);
}

// Round 2
// 1022.773 us; speedup vs baseline: 1.2349x; 1.2349x over previous
//
#include <hip/hip_runtime.h>
#include <stdint.h>

typedef unsigned short u16;
typedef unsigned char u8;
typedef __attribute__((ext_vector_type(8))) short short8;
typedef __attribute__((ext_vector_type(4))) float f32x4;

#define NSTEP 26
#define NB 512
#define NT 128
#define NH 256
#define NCLS 100

#define SP 32.0f     // proj_H int8 scale (clamps |x|>3.97 where tanh is saturated)
#define SH 24.0f     // batch_H int8 scale
#define SW 2000.0f   // W_h2h int8 scale (|w| <= 1/16 -> |q| <= 125, near-exact)

__device__ __forceinline__ float bf2f(u16 s) { return __uint_as_float(((unsigned)s) << 16); }
__device__ __forceinline__ u16 f2bf(float f) {
    unsigned u = __float_as_uint(f);
    return (u16)((u + 0x7FFFu + ((u >> 16) & 1u)) >> 16);
}
__device__ __forceinline__ int q8i(float x, float s) {
    float v = fminf(fmaxf(x * s, -127.f), 127.f);
    return __float2int_rn(v);
}
__device__ __forceinline__ float fast_tanh(float x) {
    float e = __expf(2.f * x);
    return 1.f - 2.f / (e + 1.f);
}
__device__ __forceinline__ float fast_sig(float x) { return 1.f / (1.f + __expf(-x)); }
// Pade tanh, |err|<=0.02 abs on useful range, clamped so it saturates correctly
__device__ __forceinline__ float ptanh(float x) {
    float x2 = x * x;
    float r = (x * (27.f + x2)) * __frcp_rn(27.f + 9.f * x2);
    return fminf(fmaxf(r, -1.f), 1.f);
}

// ---------------- prep: weight conversions ----------------
__global__ void prep_weights(const float* __restrict__ W_h2h, const float* __restrict__ W_i2h,
                             const float* __restrict__ W_ih, const float* __restrict__ W_hh,
                             const float* __restrict__ b_ih, const float* __restrict__ b_hh,
                             const float* __restrict__ W_gen,
                             char* __restrict__ Wh2h_q8, u16* __restrict__ Wi2h_bf,
                             u16* __restrict__ Wcat, float* __restrict__ bsum,
                             u16* __restrict__ WgenP) {
    int idx = blockIdx.x * 256 + threadIdx.x;  // 65536 threads
    if (idx < 65536) {
        Wh2h_q8[idx] = (char)q8i(W_h2h[idx], SW);
        Wi2h_bf[idx] = f2bf(W_i2h[idx]);
    }
    for (int i = idx; i < 1024 * 512; i += 65536) {
        int r = i >> 9, c = i & 511;
        float v = (c < 256) ? W_ih[r * 356 + c] : W_hh[r * 256 + (c - 256)];
        Wcat[i] = f2bf(v);
    }
    if (idx < 1024) bsum[idx] = b_ih[idx] + b_hh[idx];
    if (idx < 128 * 256) {
        int r = idx >> 8, c = idx & 255;
        WgenP[idx] = (r < NCLS) ? f2bf(W_gen[r * 256 + c]) : (u16)0;
    }
}

// ---------------- proj_H GEMM, full-N tile, fused bHf8 emit, int8 outputs ----------------
// grid 1024: block mb covers rows m in [mb*64, mb*64+64)  (m = b*128 + t), all 256 n (=h).
__launch_bounds__(256)
__global__ void gemm_projH2(const float* __restrict__ bH, const u16* __restrict__ Wi2h_bf,
                            char* __restrict__ projF8, char* __restrict__ bHf8) {
    __shared__ u16 As[64 * 32];
    __shared__ u16 Bs[256 * 32];  // 16 KB; reused as Tt char[256][64] in epilogue
    int mb = blockIdx.x, tid = threadIdx.x;
    int wave = tid >> 6, lane = tid & 63, lr = lane & 15, lq = lane >> 4;
    int b = (mb * 64) >> 7;
    int t0 = (mb & 1) * 64;
    f32x4 acc[16] = {};

    for (int kc = 0; kc < 256; kc += 32) {
        __syncthreads();
        {   // A tile 64x32 (+ emit bHf8 int8, each element exactly once)
            int r = tid >> 2, c = (tid & 3) * 8;
            const float* src = bH + (size_t)(mb * 64 + r) * 256 + kc + c;
            float4 v0 = *(const float4*)(src);
            float4 v1 = *(const float4*)(src + 4);
            u16* dst = As + r * 32 + c;
            dst[0] = f2bf(v0.x); dst[1] = f2bf(v0.y); dst[2] = f2bf(v0.z); dst[3] = f2bf(v0.w);
            dst[4] = f2bf(v1.x); dst[5] = f2bf(v1.y); dst[6] = f2bf(v1.z); dst[7] = f2bf(v1.w);
            uint p0 = (uint)(u8)q8i(v0.x, SH) | ((uint)(u8)q8i(v0.y, SH) << 8) |
                      ((uint)(u8)q8i(v0.z, SH) << 16) | ((uint)(u8)q8i(v0.w, SH) << 24);
            uint p1 = (uint)(u8)q8i(v1.x, SH) | ((uint)(u8)q8i(v1.y, SH) << 8) |
                      ((uint)(u8)q8i(v1.z, SH) << 16) | ((uint)(u8)q8i(v1.w, SH) << 24);
            uint2 pk = {p0, p1};
            *(uint2*)(bHf8 + (size_t)(mb * 64 + r) * 256 + kc + c) = pk;
        }
        {   // B tile 256x32 from bf16 W_i2h
            int p = tid & 3;
            for (int rr = tid >> 2; rr < 256; rr += 64) {
                short8 v = *(const short8*)(Wi2h_bf + (size_t)rr * 256 + kc + p * 8);
                *(short8*)(Bs + rr * 32 + p * 8) = v;
            }
        }
        __syncthreads();
        short8 a = *reinterpret_cast<const short8*>(As + (wave * 16 + lr) * 32 + lq * 8);
        for (int nt = 0; nt < 16; nt++) {
            short8 bf = *reinterpret_cast<const short8*>(Bs + (nt * 16 + lr) * 32 + lq * 8);
            acc[nt] = __builtin_amdgcn_mfma_f32_16x16x32_bf16(a, bf, acc[nt], 0, 0, 0);
        }
    }
    __syncthreads();
    char* Tt = (char*)Bs;  // [n=256][tl=64]
    {
        int ml = wave * 16 + lq * 4;
        for (int nt = 0; nt < 16; nt++) {
            int n = nt * 16 + lr;
            uint pk = (uint)(u8)q8i(acc[nt][0], SP) | ((uint)(u8)q8i(acc[nt][1], SP) << 8) |
                      ((uint)(u8)q8i(acc[nt][2], SP) << 16) | ((uint)(u8)q8i(acc[nt][3], SP) << 24);
            *(uint*)(Tt + n * 64 + ml) = pk;
        }
    }
    __syncthreads();
    {
        int p = tid & 3;
        for (int rr = tid >> 2; rr < 256; rr += 64) {
            uint4 v = *(uint4*)(Tt + rr * 64 + p * 16);
            *(uint4*)(projF8 + (size_t)b * 32768 + rr * 128 + t0 + p * 16) = v;
        }
    }
}

// ---------------- per-step fused attention (int8 data path) ----------------
__launch_bounds__(256)
__global__ void attn_step2(const float* __restrict__ h_all, const char* __restrict__ Wh2h_q8,
                           const float* __restrict__ b_h2h, const float* __restrict__ W_score,
                           const char* __restrict__ projF8, const char* __restrict__ bHf8,
                           u16* __restrict__ Xcat, int step) {
    __shared__ float h_s[256];
    __shared__ float ph[256];
    __shared__ float ws_s[256];
    __shared__ float epart[128 * 16];
    __shared__ float e_s[128];
    __shared__ float red[2];
    __shared__ float cpart[256 * 4];
    int b = blockIdx.x, tid = threadIdx.x;

    float hv = (step > 0) ? h_all[(size_t)(step - 1) * NB * NH + b * NH + tid] : 0.f;
    h_s[tid] = hv;
    ws_s[tid] = W_score[tid];
    Xcat[b * 512 + 256 + tid] = f2bf(hv);
    __syncthreads();

    // ph[u] = b_h2h[u] + (h . Wq8[u,:]) / SW
    {
        float acc = 0.f;
        const char* wrow = Wh2h_q8 + (size_t)tid * 256;
        for (int k = 0; k < 256; k += 16) {
            uint4 u = *(const uint4*)(wrow + k);
            uint w = u.x;
            acc += h_s[k + 0] * (float)(char)(w) + h_s[k + 1] * (float)(char)(w >> 8) +
                   h_s[k + 2] * (float)(char)(w >> 16) + h_s[k + 3] * (float)(char)(w >> 24);
            w = u.y;
            acc += h_s[k + 4] * (float)(char)(w) + h_s[k + 5] * (float)(char)(w >> 8) +
                   h_s[k + 6] * (float)(char)(w >> 16) + h_s[k + 7] * (float)(char)(w >> 24);
            w = u.z;
            acc += h_s[k + 8] * (float)(char)(w) + h_s[k + 9] * (float)(char)(w >> 8) +
                   h_s[k + 10] * (float)(char)(w >> 16) + h_s[k + 11] * (float)(char)(w >> 24);
            w = u.w;
            acc += h_s[k + 12] * (float)(char)(w) + h_s[k + 13] * (float)(char)(w >> 8) +
                   h_s[k + 14] * (float)(char)(w >> 16) + h_s[k + 15] * (float)(char)(w >> 24);
        }
        ph[tid] = acc * (1.f / SW) + b_h2h[tid];
    }
    __syncthreads();

    // e[t] = sum_h tanh(projF8/SP + ph[h]) * Ws[h]; thread = (t-group of 8) x (h-group of 16)
    {
        int tq = tid & 15, hg = tid >> 4;
        int t0 = tq * 8;
        const char* base = projF8 + (size_t)b * 32768 + (hg * 16) * 128 + t0;
        float a8[8] = {};
        for (int hh = 0; hh < 16; hh++) {
            uint2 u = *(const uint2*)(base + hh * 128);
            float phv = ph[hg * 16 + hh];
            float wv = ws_s[hg * 16 + hh];
            uint w = u.x;
            a8[0] += ptanh((float)(char)(w) * (1.f / SP) + phv) * wv;
            a8[1] += ptanh((float)(char)(w >> 8) * (1.f / SP) + phv) * wv;
            a8[2] += ptanh((float)(char)(w >> 16) * (1.f / SP) + phv) * wv;
            a8[3] += ptanh((float)(char)(w >> 24) * (1.f / SP) + phv) * wv;
            w = u.y;
            a8[4] += ptanh((float)(char)(w) * (1.f / SP) + phv) * wv;
            a8[5] += ptanh((float)(char)(w >> 8) * (1.f / SP) + phv) * wv;
            a8[6] += ptanh((float)(char)(w >> 16) * (1.f / SP) + phv) * wv;
            a8[7] += ptanh((float)(char)(w >> 24) * (1.f / SP) + phv) * wv;
        }
        for (int j = 0; j < 8; j++) epart[(t0 + j) * 16 + hg] = a8[j];
    }
    __syncthreads();
    if (tid < 128) {
        float s = 0.f;
        for (int g = 0; g < 16; g++) s += epart[tid * 16 + g];
        e_s[tid] = s;
    }
    __syncthreads();

    // softmax over t
    if (tid < 64) {
        float v = fmaxf(e_s[tid], e_s[tid + 64]);
        for (int o = 32; o >= 1; o >>= 1) v = fmaxf(v, __shfl_down(v, o));
        if (tid == 0) red[0] = v;
    }
    __syncthreads();
    float mx = red[0];
    if (tid < 128) e_s[tid] = __expf(e_s[tid] - mx);
    __syncthreads();
    if (tid < 64) {
        float v = e_s[tid] + e_s[tid + 64];
        for (int o = 32; o >= 1; o >>= 1) v += __shfl_down(v, o);
        if (tid == 0) red[1] = 1.f / v;
    }
    __syncthreads();
    float rinv = red[1];

    // context[i] = (sum_t alpha_t * bHf8[b][t][i]) * rinv / SH
    {
        int cidx = tid & 63, ts = tid >> 6;
        float a4[4] = {};
        const char* bb = bHf8 + (size_t)b * 32768 + cidx * 4;
        for (int it = 0; it < 32; it++) {
            int t = it * 4 + ts;
            uint u = *(const uint*)(bb + (size_t)t * 256);
            float al = e_s[t];
            a4[0] += al * (float)(char)(u);
            a4[1] += al * (float)(char)(u >> 8);
            a4[2] += al * (float)(char)(u >> 16);
            a4[3] += al * (float)(char)(u >> 24);
        }
        for (int j = 0; j < 4; j++) cpart[(cidx * 4 + j) * 4 + ts] = a4[j];
    }
    __syncthreads();
    {
        float s = cpart[tid * 4 + 0] + cpart[tid * 4 + 1] + cpart[tid * 4 + 2] + cpart[tid * 4 + 3];
        Xcat[b * 512 + tid] = f2bf(s * rinv * (1.f / SH));
    }
}

// ---------------- per-step LSTM (unchanged from R1, passed) ----------------
__launch_bounds__(256)
__global__ void lstm_step(const u16* __restrict__ Xcat, const u16* __restrict__ Wcat,
                          const float* __restrict__ bsum, const float* __restrict__ W_ih,
                          const int* __restrict__ text, float* __restrict__ c_st,
                          float* __restrict__ h_all, u16* __restrict__ hbf_all, int step) {
    __shared__ u16 Xs[32 * 32];
    __shared__ u16 Ws[128 * 32];
    __shared__ float gsum[32 * 128];
    int b0 = blockIdx.x * 32;
    int u0 = blockIdx.y * 32;
    int tid = threadIdx.x;
    int wave = tid >> 6, lane = tid & 63, lr = lane & 15, lq = lane >> 4;
    int wm = wave >> 1, wn = wave & 1;
    f32x4 acc[4] = {};

    for (int kc = 0; kc < 512; kc += 32) {
        __syncthreads();
        {
            int r = tid >> 3, c4 = (tid & 7) * 4;
            *(ushort4*)(Xs + r * 32 + c4) = *(const ushort4*)(Xcat + (size_t)(b0 + r) * 512 + kc + c4);
        }
        {
            int ln = tid >> 1, h16 = (tid & 1) * 16;
            int grow = (ln >> 5) * 256 + u0 + (ln & 31);
            const u16* src = Wcat + (size_t)grow * 512 + kc + h16;
            u16* d = Ws + ln * 32 + h16;
            *(ushort4*)(d) = *(const ushort4*)(src);
            *(ushort4*)(d + 4) = *(const ushort4*)(src + 4);
            *(ushort4*)(d + 8) = *(const ushort4*)(src + 8);
            *(ushort4*)(d + 12) = *(const ushort4*)(src + 12);
        }
        __syncthreads();
        short8 a = *reinterpret_cast<const short8*>(Xs + (wm * 16 + lr) * 32 + lq * 8);
        for (int ni = 0; ni < 4; ni++) {
            short8 bb = *reinterpret_cast<const short8*>(Ws + (wn * 64 + ni * 16 + lr) * 32 + lq * 8);
            acc[ni] = __builtin_amdgcn_mfma_f32_16x16x32_bf16(a, bb, acc[ni], 0, 0, 0);
        }
    }
    for (int ni = 0; ni < 4; ni++) {
        int n = wn * 64 + ni * 16 + lr;
        int m = wm * 16 + lq * 4;
        gsum[(m + 0) * 128 + n] = acc[ni][0];
        gsum[(m + 1) * 128 + n] = acc[ni][1];
        gsum[(m + 2) * 128 + n] = acc[ni][2];
        gsum[(m + 3) * 128 + n] = acc[ni][3];
    }
    __syncthreads();

    int m = tid >> 3;
    int bg = b0 + m;
    int tgt = text[bg * NSTEP + step];
    for (int j = 0; j < 4; j++) {
        int uu = (tid & 7) * 4 + j;
        int u = u0 + uu;
        int ri = u, rf = 256 + u, rg = 512 + u, ro = 768 + u;
        float gi = gsum[m * 128 + 0 * 32 + uu] + bsum[ri] + W_ih[(size_t)ri * 356 + 256 + tgt];
        float gf = gsum[m * 128 + 1 * 32 + uu] + bsum[rf] + W_ih[(size_t)rf * 356 + 256 + tgt];
        float gg = gsum[m * 128 + 2 * 32 + uu] + bsum[rg] + W_ih[(size_t)rg * 356 + 256 + tgt];
        float go = gsum[m * 128 + 3 * 32 + uu] + bsum[ro] + W_ih[(size_t)ro * 356 + 256 + tgt];
        float cold = (step > 0) ? c_st[bg * 256 + u] : 0.f;
        float cn = fast_sig(gf) * cold + fast_sig(gi) * fast_tanh(gg);
        float hn = fast_sig(go) * fast_tanh(cn);
        c_st[bg * 256 + u] = cn;
        h_all[(size_t)step * NB * NH + bg * 256 + u] = hn;
        hbf_all[(size_t)step * NB * NH + bg * 256 + u] = f2bf(hn);
    }
}

// ---------------- final logits (unchanged from R1, passed) ----------------
__launch_bounds__(256)
__global__ void gen_logits(const u16* __restrict__ hbf_all, const u16* __restrict__ WgenP,
                           const float* __restrict__ b_gen, float* __restrict__ out) {
    __shared__ u16 As[32 * 32];
    __shared__ u16 Bs[128 * 32];
    int mb = blockIdx.x;
    int tid = threadIdx.x;
    int wave = tid >> 6, lane = tid & 63, lr = lane & 15, lq = lane >> 4;
    int wm = wave >> 1, wn = wave & 1;
    f32x4 acc[4] = {};
    for (int kc = 0; kc < 256; kc += 32) {
        __syncthreads();
        {
            int r = tid >> 3, c4 = (tid & 7) * 4;
            *(ushort4*)(As + r * 32 + c4) =
                *(const ushort4*)(hbf_all + (size_t)(mb * 32 + r) * 256 + kc + c4);
        }
        {
            int r = tid >> 1, h16 = (tid & 1) * 16;
            const u16* src = WgenP + (size_t)r * 256 + kc + h16;
            u16* d = Bs + r * 32 + h16;
            *(ushort4*)(d) = *(const ushort4*)(src);
            *(ushort4*)(d + 4) = *(const ushort4*)(src + 4);
            *(ushort4*)(d + 8) = *(const ushort4*)(src + 8);
            *(ushort4*)(d + 12) = *(const ushort4*)(src + 12);
        }
        __syncthreads();
        short8 a = *reinterpret_cast<const short8*>(As + (wm * 16 + lr) * 32 + lq * 8);
        for (int ni = 0; ni < 4; ni++) {
            short8 bb = *reinterpret_cast<const short8*>(Bs + (wn * 64 + ni * 16 + lr) * 32 + lq * 8);
            acc[ni] = __builtin_amdgcn_mfma_f32_16x16x32_bf16(a, bb, acc[ni], 0, 0, 0);
        }
    }
    for (int ni = 0; ni < 4; ni++) {
        int cidx = wn * 64 + ni * 16 + lr;
        if (cidx >= NCLS) continue;
        float bg = b_gen[cidx];
        int mbase = mb * 32 + wm * 16 + lq * 4;
        for (int r = 0; r < 4; r++) {
            int mm = mbase + r;
            int s = mm >> 9;
            int bb_ = mm & 511;
            float v = (cidx == 3) ? -10000.f : (acc[ni][r] + bg);
            out[(size_t)bb_ * (NSTEP * NCLS) + s * NCLS + cidx] = v;
        }
    }
}

extern "C" void kernel_launch(void* const* d_in, const int* in_sizes, int n_in,
                              void* d_out, int out_size, void* d_ws, size_t ws_size,
                              hipStream_t stream) {
    const float* batch_H = (const float*)d_in[0];
    const int* text = (const int*)d_in[1];
    const float* W_i2h = (const float*)d_in[3];
    const float* W_h2h = (const float*)d_in[4];
    const float* b_h2h = (const float*)d_in[5];
    const float* W_score = (const float*)d_in[6];
    const float* W_ih = (const float*)d_in[7];
    const float* W_hh = (const float*)d_in[8];
    const float* b_ih = (const float*)d_in[9];
    const float* b_hh = (const float*)d_in[10];
    const float* W_gen = (const float*)d_in[11];
    const float* b_gen = (const float*)d_in[12];
    float* out = (float*)d_out;

    char* ws = (char*)d_ws;
    size_t off = 0;
    auto alloc = [&](size_t bytes) {
        void* p = ws + off;
        off += (bytes + 255) & ~(size_t)255;
        return p;
    };
    char* projF8 = (char*)alloc((size_t)16777216);    // [b][h][t] int8
    char* bHf8 = (char*)alloc((size_t)16777216);      // [b][t][i] int8
    char* Wh2h_q8 = (char*)alloc(65536);
    u16* Wi2h_bf = (u16*)alloc(65536 * 2);
    u16* Wcat = (u16*)alloc(524288 * 2);
    float* bsum = (float*)alloc(1024 * 4);
    u16* WgenP = (u16*)alloc(32768 * 2);
    u16* Xcat = (u16*)alloc(262144 * 2);
    float* h_all = (float*)alloc((size_t)NSTEP * NB * NH * 4);
    u16* hbf_all = (u16*)alloc((size_t)NSTEP * NB * NH * 2);
    float* c_st = (float*)alloc((size_t)NB * NH * 4);

    prep_weights<<<256, 256, 0, stream>>>(W_h2h, W_i2h, W_ih, W_hh, b_ih, b_hh, W_gen,
                                          Wh2h_q8, Wi2h_bf, Wcat, bsum, WgenP);
    gemm_projH2<<<1024, 256, 0, stream>>>(batch_H, Wi2h_bf, projF8, bHf8);
    for (int s = 0; s < NSTEP; s++) {
        attn_step2<<<512, 256, 0, stream>>>(h_all, Wh2h_q8, b_h2h, W_score, projF8, bHf8, Xcat, s);
        lstm_step<<<dim3(16, 8), 256, 0, stream>>>(Xcat, Wcat, bsum, W_ih, text, c_st,
                                                   h_all, hbf_all, s);
    }
    gen_logits<<<416, 256, 0, stream>>>(hbf_all, WgenP, b_gen, out);
}

// Round 3
// 944.849 us; speedup vs baseline: 1.3367x; 1.0825x over previous
//
#include <hip/hip_runtime.h>
#include <stdint.h>

typedef unsigned short u16;
typedef unsigned char u8;
typedef unsigned int u32;
typedef __attribute__((ext_vector_type(8))) short short8;
typedef __attribute__((ext_vector_type(4))) float f32x4;

#define NSTEP 26
#define NB 512
#define NT 128
#define NH 256
#define NCLS 100

#define SP 32.0f     // proj_H int8 scale
#define SH 24.0f     // batch_H int8 scale
#define SW 2000.0f   // W_h2h int8 scale

__device__ __forceinline__ float bf2f(u16 s) { return __uint_as_float(((unsigned)s) << 16); }
__device__ __forceinline__ u16 f2bf(float f) {
    unsigned u = __float_as_uint(f);
    return (u16)((u + 0x7FFFu + ((u >> 16) & 1u)) >> 16);
}
__device__ __forceinline__ int q8i(float x, float s) {
    float v = fminf(fmaxf(x * s, -127.f), 127.f);
    return __float2int_rn(v);
}
__device__ __forceinline__ float fast_tanh(float x) {
    float e = __expf(2.f * x);
    return 1.f - 2.f / (e + 1.f);
}
__device__ __forceinline__ float fast_sig(float x) { return 1.f / (1.f + __expf(-x)); }
__device__ __forceinline__ float ptanh(float x) {
    float x2 = x * x;
    float r = (x * (27.f + x2)) * __frcp_rn(27.f + 9.f * x2);
    return fminf(fmaxf(r, -1.f), 1.f);
}
// async global->LDS, 16B per lane. lptr must be (uniform base + lane*16).
__device__ __forceinline__ void async_g2l(const void* g, void* l) {
    __builtin_amdgcn_global_load_lds((const __attribute__((address_space(1))) u32*)g,
                                     (__attribute__((address_space(3))) u32*)l, 16, 0, 0);
}

// ---------------- prep: weight conversions ----------------
// Wcat3: B-fragment-swizzled LSTM weights: [(ub*16+ks)*4+q][lane 64][j 8] bf16
//   content: row (q*256+ub*16+(lane&15)), k = ks*32+(lane>>4)*8+j  of [W_ih[:,:256]|W_hh]
// WohT: [tgt 100][gate-row 1024] fp32 = W_ih[:,256+tgt] transposed
__global__ void prep_weights(const float* __restrict__ W_h2h, const float* __restrict__ W_i2h,
                             const float* __restrict__ W_ih, const float* __restrict__ W_hh,
                             const float* __restrict__ b_ih, const float* __restrict__ b_hh,
                             const float* __restrict__ W_gen,
                             char* __restrict__ Wh2h_q8, u16* __restrict__ Wi2h_bf,
                             u16* __restrict__ Wcat3, float* __restrict__ bsum,
                             u16* __restrict__ WgenP, float* __restrict__ WohT) {
    int idx = blockIdx.x * 256 + threadIdx.x;  // 65536 threads
    if (idx < 65536) {
        Wh2h_q8[idx] = (char)q8i(W_h2h[idx], SW);
        Wi2h_bf[idx] = f2bf(W_i2h[idx]);
    }
    for (int i = idx; i < 16 * 16 * 4 * 64 * 8; i += 65536) {
        int j = i & 7, lane = (i >> 3) & 63, q = (i >> 9) & 3, ks = (i >> 11) & 15, ub = i >> 15;
        int lr = lane & 15, lq = lane >> 4;
        int rg = q * 256 + ub * 16 + lr;
        int k = ks * 32 + lq * 8 + j;
        float v = (k < 256) ? W_ih[(size_t)rg * 356 + k] : W_hh[(size_t)rg * 256 + (k - 256)];
        Wcat3[i] = f2bf(v);
    }
    for (int i = idx; i < 100 * 1024; i += 65536) {
        int t = i >> 10, rg = i & 1023;
        WohT[i] = W_ih[(size_t)rg * 356 + 256 + t];
    }
    if (idx < 1024) bsum[idx] = b_ih[idx] + b_hh[idx];
    if (idx < 128 * 256) {
        int r = idx >> 8, c = idx & 255;
        WgenP[idx] = (r < NCLS) ? f2bf(W_gen[r * 256 + c]) : (u16)0;
    }
}

// ---------------- proj_H GEMM, M=32 tile, full N=256, int8 outputs ----------------
__launch_bounds__(256)
__global__ void gemm_projH3(const float* __restrict__ bH, const u16* __restrict__ Wi2h_bf,
                            char* __restrict__ projF8, char* __restrict__ bHf8) {
    __shared__ u16 As[32 * 32];
    __shared__ u16 Bs[256 * 32];
    int mb = blockIdx.x, tid = threadIdx.x;
    int wave = tid >> 6, lane = tid & 63, lr = lane & 15, lq = lane >> 4;
    int wm = wave >> 1, wn = wave & 1;
    int b = mb >> 2;
    int t0 = (mb & 3) * 32;
    f32x4 acc[8] = {};

    for (int kc = 0; kc < 256; kc += 32) {
        __syncthreads();
        {   // A tile 32x32 + bHf8 emit (each element exactly once)
            int r = tid >> 3, c4 = (tid & 7) * 4;
            const float* src = bH + (size_t)(mb * 32 + r) * 256 + kc + c4;
            float4 v = *(const float4*)(src);
            u16* dst = As + r * 32 + c4;
            dst[0] = f2bf(v.x); dst[1] = f2bf(v.y); dst[2] = f2bf(v.z); dst[3] = f2bf(v.w);
            uint pk = (uint)(u8)q8i(v.x, SH) | ((uint)(u8)q8i(v.y, SH) << 8) |
                      ((uint)(u8)q8i(v.z, SH) << 16) | ((uint)(u8)q8i(v.w, SH) << 24);
            *(uint*)(bHf8 + (size_t)(mb * 32 + r) * 256 + kc + c4) = pk;
        }
        {   // B tile 256x32
            int p = tid & 3;
            for (int rr = tid >> 2; rr < 256; rr += 64) {
                short8 v = *(const short8*)(Wi2h_bf + (size_t)rr * 256 + kc + p * 8);
                *(short8*)(Bs + rr * 32 + p * 8) = v;
            }
        }
        __syncthreads();
        short8 a = *reinterpret_cast<const short8*>(As + (wm * 16 + lr) * 32 + lq * 8);
        for (int ni = 0; ni < 8; ni++) {
            short8 bf = *reinterpret_cast<const short8*>(Bs + (wn * 128 + ni * 16 + lr) * 32 + lq * 8);
            acc[ni] = __builtin_amdgcn_mfma_f32_16x16x32_bf16(a, bf, acc[ni], 0, 0, 0);
        }
    }
    __syncthreads();
    char* Tt = (char*)Bs;  // [n=256][tl=32] int8
    {
        int ml = wm * 16 + lq * 4;
        for (int ni = 0; ni < 8; ni++) {
            int n = wn * 128 + ni * 16 + lr;
            uint pk = (uint)(u8)q8i(acc[ni][0], SP) | ((uint)(u8)q8i(acc[ni][1], SP) << 8) |
                      ((uint)(u8)q8i(acc[ni][2], SP) << 16) | ((uint)(u8)q8i(acc[ni][3], SP) << 24);
            *(uint*)(Tt + n * 32 + ml) = pk;
        }
    }
    __syncthreads();
    {   // write out: thread = one h-row, 32 t values
        int rr = tid;
        uint4 v0 = *(uint4*)(Tt + rr * 32);
        uint4 v1 = *(uint4*)(Tt + rr * 32 + 16);
        char* dst = projF8 + (size_t)b * 32768 + rr * 128 + t0;
        *(uint4*)(dst) = v0;
        *(uint4*)(dst + 16) = v1;
    }
}

// ---------------- per-step fused attention, async-LDS prefetch ----------------
// writes XcatS in MFMA A-frag order: [btile 32][ks 16][lane 64][j 8] bf16
__launch_bounds__(256)
__global__ void attn_step3(const float* __restrict__ h_all, const char* __restrict__ Wh2h_q8,
                           const float* __restrict__ b_h2h, const float* __restrict__ W_score,
                           const char* __restrict__ projF8, const char* __restrict__ bHf8,
                           u16* __restrict__ XcatS, int step) {
    __shared__ char projL[32 * 1056];  // 32 chunks of 1KB + 32B pad
    __shared__ float h_s[256];
    __shared__ float ph[256];
    __shared__ float ws_s[256];
    __shared__ float epart[128 * 16];
    __shared__ float e_s[128];
    __shared__ float red[2];
    __shared__ float cpart[256 * 4];
    int b = blockIdx.x, tid = threadIdx.x;
    int wave = tid >> 6, lane = tid & 63;
    int btile = b >> 4, blr = b & 15;

    // issue async prefetch of this block's projF8 slice (32 KB)
    {
        const char* gsrc = projF8 + (size_t)b * 32768;
        for (int i = 0; i < 8; i++) {
            int c = wave * 8 + i;
            async_g2l(gsrc + c * 1024 + lane * 16, projL + c * 1056 + lane * 16);
        }
    }

    float hv = (step > 0) ? h_all[(size_t)(step - 1) * NB * NH + b * NH + tid] : 0.f;
    h_s[tid] = hv;
    ws_s[tid] = W_score[tid];
    {   // h half of XcatS: value k = 256+tid
        int k = 256 + tid;
        int ks = k >> 5, lq = (k >> 3) & 3, j = k & 7;
        XcatS[(size_t)((btile * 16 + ks) * 64 + lq * 16 + blr) * 8 + j] = f2bf(hv);
    }
    __syncthreads();

    // ph[u] = b_h2h[u] + (h . Wq8[u,:]) / SW   (overlaps with async loads in flight)
    {
        float acc = 0.f;
        const char* wrow = Wh2h_q8 + (size_t)tid * 256;
        for (int k = 0; k < 256; k += 16) {
            uint4 u = *(const uint4*)(wrow + k);
            uint w = u.x;
            acc += h_s[k + 0] * (float)(char)(w) + h_s[k + 1] * (float)(char)(w >> 8) +
                   h_s[k + 2] * (float)(char)(w >> 16) + h_s[k + 3] * (float)(char)(w >> 24);
            w = u.y;
            acc += h_s[k + 4] * (float)(char)(w) + h_s[k + 5] * (float)(char)(w >> 8) +
                   h_s[k + 6] * (float)(char)(w >> 16) + h_s[k + 7] * (float)(char)(w >> 24);
            w = u.z;
            acc += h_s[k + 8] * (float)(char)(w) + h_s[k + 9] * (float)(char)(w >> 8) +
                   h_s[k + 10] * (float)(char)(w >> 16) + h_s[k + 11] * (float)(char)(w >> 24);
            w = u.w;
            acc += h_s[k + 12] * (float)(char)(w) + h_s[k + 13] * (float)(char)(w >> 8) +
                   h_s[k + 14] * (float)(char)(w >> 16) + h_s[k + 15] * (float)(char)(w >> 24);
        }
        ph[tid] = acc * (1.f / SW) + b_h2h[tid];
    }
    __syncthreads();  // drains vmcnt -> async LDS loads complete

    // e[t] = sum_h tanh(projL/SP + ph[h]) * Ws[h]
    {
        int tq = tid & 15, hg = tid >> 4;
        int t0 = tq * 8;
        float a8[8] = {};
        for (int hh = 0; hh < 16; hh++) {
            int R = hg * 16 + hh;
            const char* p = projL + (R >> 3) * 1056 + (R & 7) * 128 + t0;
            uint2 u = *(const uint2*)(p);
            float phv = ph[R];
            float wv = ws_s[R];
            uint w = u.x;
            a8[0] += ptanh((float)(char)(w) * (1.f / SP) + phv) * wv;
            a8[1] += ptanh((float)(char)(w >> 8) * (1.f / SP) + phv) * wv;
            a8[2] += ptanh((float)(char)(w >> 16) * (1.f / SP) + phv) * wv;
            a8[3] += ptanh((float)(char)(w >> 24) * (1.f / SP) + phv) * wv;
            w = u.y;
            a8[4] += ptanh((float)(char)(w) * (1.f / SP) + phv) * wv;
            a8[5] += ptanh((float)(char)(w >> 8) * (1.f / SP) + phv) * wv;
            a8[6] += ptanh((float)(char)(w >> 16) * (1.f / SP) + phv) * wv;
            a8[7] += ptanh((float)(char)(w >> 24) * (1.f / SP) + phv) * wv;
        }
        for (int j = 0; j < 8; j++) epart[(t0 + j) * 16 + hg] = a8[j];
    }
    __syncthreads();
    if (tid < 128) {
        float s = 0.f;
        for (int g = 0; g < 16; g++) s += epart[tid * 16 + g];
        e_s[tid] = s;
    }
    __syncthreads();

    // softmax over t
    if (tid < 64) {
        float v = fmaxf(e_s[tid], e_s[tid + 64]);
        for (int o = 32; o >= 1; o >>= 1) v = fmaxf(v, __shfl_down(v, o));
        if (tid == 0) red[0] = v;
    }
    __syncthreads();
    float mx = red[0];
    if (tid < 128) e_s[tid] = __expf(e_s[tid] - mx);
    __syncthreads();
    if (tid < 64) {
        float v = e_s[tid] + e_s[tid + 64];
        for (int o = 32; o >= 1; o >>= 1) v += __shfl_down(v, o);
        if (tid == 0) red[1] = 1.f / v;
    }
    __syncthreads();
    float rinv = red[1];

    // context[i] = (sum_t alpha_t * bHf8[b][t][i]) * rinv / SH
    {
        int cidx = tid & 63, ts = tid >> 6;
        float a4[4] = {};
        const char* bb = bHf8 + (size_t)b * 32768 + cidx * 4;
        for (int it = 0; it < 32; it++) {
            int t = it * 4 + ts;
            uint u = *(const uint*)(bb + (size_t)t * 256);
            float al = e_s[t];
            a4[0] += al * (float)(char)(u);
            a4[1] += al * (float)(char)(u >> 8);
            a4[2] += al * (float)(char)(u >> 16);
            a4[3] += al * (float)(char)(u >> 24);
        }
        for (int j = 0; j < 4; j++) cpart[(cidx * 4 + j) * 4 + ts] = a4[j];
    }
    __syncthreads();
    {   // context value k = tid -> XcatS A-frag position
        float s = cpart[tid * 4 + 0] + cpart[tid * 4 + 1] + cpart[tid * 4 + 2] + cpart[tid * 4 + 3];
        int k = tid;
        int ks = k >> 5, lq = (k >> 3) & 3, j = k & 7;
        XcatS[(size_t)((btile * 16 + ks) * 64 + lq * 16 + blr) * 8 + j] = f2bf(s * rinv * (1.f / SH));
    }
}

// ---------------- per-step LSTM: zero-LDS, zero-barrier, frag-streamed ----------------
__launch_bounds__(256)
__global__ void lstm_step4(const u16* __restrict__ XcatS, const u16* __restrict__ Wcat3,
                           const float* __restrict__ bsum, const float* __restrict__ WohT,
                           const int* __restrict__ text, float* __restrict__ c_st,
                           float* __restrict__ h_all, u16* __restrict__ hbf_all, int step) {
    int tid = threadIdx.x;
    int wave = tid >> 6, lane = tid & 63, lr = lane & 15, lq = lane >> 4;
    int job = blockIdx.x * 4 + wave;   // 512 jobs
    int mt = job >> 4;                 // m-tile: batches mt*16..+16
    int ub = job & 15;                 // unit group: units ub*16..+16
    f32x4 acc[4] = {};

    for (int ks = 0; ks < 16; ks++) {
        short8 a = *(const short8*)(XcatS + (size_t)((mt * 16 + ks) * 64 + lane) * 8);
        const u16* wb = Wcat3 + (size_t)((ub * 16 + ks) * 4) * 512 + lane * 8;
        short8 b0 = *(const short8*)(wb);
        short8 b1 = *(const short8*)(wb + 512);
        short8 b2 = *(const short8*)(wb + 1024);
        short8 b3 = *(const short8*)(wb + 1536);
        acc[0] = __builtin_amdgcn_mfma_f32_16x16x32_bf16(a, b0, acc[0], 0, 0, 0);
        acc[1] = __builtin_amdgcn_mfma_f32_16x16x32_bf16(a, b1, acc[1], 0, 0, 0);
        acc[2] = __builtin_amdgcn_mfma_f32_16x16x32_bf16(a, b2, acc[2], 0, 0, 0);
        acc[3] = __builtin_amdgcn_mfma_f32_16x16x32_bf16(a, b3, acc[3], 0, 0, 0);
    }

    int u = ub * 16 + lr;
    float bi = bsum[u], bf = bsum[256 + u], bg = bsum[512 + u], bo = bsum[768 + u];
    for (int r = 0; r < 4; r++) {
        int bgi = mt * 16 + lq * 4 + r;
        int tgt = text[bgi * NSTEP + step];
        const float* wt = WohT + (size_t)tgt * 1024;
        float gi = acc[0][r] + bi + wt[u];
        float gf = acc[1][r] + bf + wt[256 + u];
        float gg = acc[2][r] + bg + wt[512 + u];
        float go = acc[3][r] + bo + wt[768 + u];
        float cold = (step > 0) ? c_st[(size_t)bgi * 256 + u] : 0.f;
        float cn = fast_sig(gf) * cold + fast_sig(gi) * fast_tanh(gg);
        float hn = fast_sig(go) * fast_tanh(cn);
        c_st[(size_t)bgi * 256 + u] = cn;
        h_all[(size_t)step * NB * NH + (size_t)bgi * 256 + u] = hn;
        hbf_all[(size_t)step * NB * NH + (size_t)bgi * 256 + u] = f2bf(hn);
    }
}

// ---------------- final logits ----------------
__launch_bounds__(256)
__global__ void gen_logits(const u16* __restrict__ hbf_all, const u16* __restrict__ WgenP,
                           const float* __restrict__ b_gen, float* __restrict__ out) {
    __shared__ u16 As[32 * 32];
    __shared__ u16 Bs[128 * 32];
    int mb = blockIdx.x;
    int tid = threadIdx.x;
    int wave = tid >> 6, lane = tid & 63, lr = lane & 15, lq = lane >> 4;
    int wm = wave >> 1, wn = wave & 1;
    f32x4 acc[4] = {};
    for (int kc = 0; kc < 256; kc += 32) {
        __syncthreads();
        {
            int r = tid >> 3, c4 = (tid & 7) * 4;
            *(ushort4*)(As + r * 32 + c4) =
                *(const ushort4*)(hbf_all + (size_t)(mb * 32 + r) * 256 + kc + c4);
        }
        {
            int r = tid >> 1, h16 = (tid & 1) * 16;
            const u16* src = WgenP + (size_t)r * 256 + kc + h16;
            u16* d = Bs + r * 32 + h16;
            *(ushort4*)(d) = *(const ushort4*)(src);
            *(ushort4*)(d + 4) = *(const ushort4*)(src + 4);
            *(ushort4*)(d + 8) = *(const ushort4*)(src + 8);
            *(ushort4*)(d + 12) = *(const ushort4*)(src + 12);
        }
        __syncthreads();
        short8 a = *reinterpret_cast<const short8*>(As + (wm * 16 + lr) * 32 + lq * 8);
        for (int ni = 0; ni < 4; ni++) {
            short8 bb = *reinterpret_cast<const short8*>(Bs + (wn * 64 + ni * 16 + lr) * 32 + lq * 8);
            acc[ni] = __builtin_amdgcn_mfma_f32_16x16x32_bf16(a, bb, acc[ni], 0, 0, 0);
        }
    }
    for (int ni = 0; ni < 4; ni++) {
        int cidx = wn * 64 + ni * 16 + lr;
        if (cidx >= NCLS) continue;
        float bg = b_gen[cidx];
        int mbase = mb * 32 + wm * 16 + lq * 4;
        for (int r = 0; r < 4; r++) {
            int mm = mbase + r;
            int s = mm >> 9;
            int bb_ = mm & 511;
            float v = (cidx == 3) ? -10000.f : (acc[ni][r] + bg);
            out[(size_t)bb_ * (NSTEP * NCLS) + s * NCLS + cidx] = v;
        }
    }
}

extern "C" void kernel_launch(void* const* d_in, const int* in_sizes, int n_in,
                              void* d_out, int out_size, void* d_ws, size_t ws_size,
                              hipStream_t stream) {
    const float* batch_H = (const float*)d_in[0];
    const int* text = (const int*)d_in[1];
    const float* W_i2h = (const float*)d_in[3];
    const float* W_h2h = (const float*)d_in[4];
    const float* b_h2h = (const float*)d_in[5];
    const float* W_score = (const float*)d_in[6];
    const float* W_ih = (const float*)d_in[7];
    const float* W_hh = (const float*)d_in[8];
    const float* b_ih = (const float*)d_in[9];
    const float* b_hh = (const float*)d_in[10];
    const float* W_gen = (const float*)d_in[11];
    const float* b_gen = (const float*)d_in[12];
    float* out = (float*)d_out;

    char* ws = (char*)d_ws;
    size_t off = 0;
    auto alloc = [&](size_t bytes) {
        void* p = ws + off;
        off += (bytes + 255) & ~(size_t)255;
        return p;
    };
    char* projF8 = (char*)alloc((size_t)16777216);    // [b][h][t] int8
    char* bHf8 = (char*)alloc((size_t)16777216);      // [b][t][i] int8
    char* Wh2h_q8 = (char*)alloc(65536);
    u16* Wi2h_bf = (u16*)alloc(65536 * 2);
    u16* Wcat3 = (u16*)alloc((size_t)524288 * 2);     // frag-swizzled LSTM weights
    float* bsum = (float*)alloc(1024 * 4);
    u16* WgenP = (u16*)alloc(32768 * 2);
    float* WohT = (float*)alloc((size_t)102400 * 4);  // [100][1024]
    u16* XcatS = (u16*)alloc((size_t)262144 * 2);     // A-frag-swizzled LSTM input
    float* h_all = (float*)alloc((size_t)NSTEP * NB * NH * 4);
    u16* hbf_all = (u16*)alloc((size_t)NSTEP * NB * NH * 2);
    float* c_st = (float*)alloc((size_t)NB * NH * 4);

    prep_weights<<<256, 256, 0, stream>>>(W_h2h, W_i2h, W_ih, W_hh, b_ih, b_hh, W_gen,
                                          Wh2h_q8, Wi2h_bf, Wcat3, bsum, WgenP, WohT);
    gemm_projH3<<<2048, 256, 0, stream>>>(batch_H, Wi2h_bf, projF8, bHf8);
    for (int s = 0; s < NSTEP; s++) {
        attn_step3<<<512, 256, 0, stream>>>(h_all, Wh2h_q8, b_h2h, W_score, projF8, bHf8,
                                            XcatS, s);
        lstm_step4<<<128, 256, 0, stream>>>(XcatS, Wcat3, bsum, WohT, text, c_st,
                                            h_all, hbf_all, s);
    }
    gen_logits<<<416, 256, 0, stream>>>(hbf_all, WgenP, b_gen, out);
}